// Round 14
// baseline (2430.291 us; speedup 1.0000x reference)
//
#include <hip/hip_runtime.h>
#include <stdint.h>
#include <stddef.h>

#define B_ 64
#define T_ 512
#define DIN 256
#define H_ 512
#define NWGF 256     // 8 groups (layer x batch-quarter) x 32 col-group WGs

typedef __attribute__((ext_vector_type(8))) short short8;
typedef __attribute__((ext_vector_type(4))) float f32x4;

typedef const __attribute__((address_space(1))) unsigned int* gas_ptr;
typedef __attribute__((address_space(3))) unsigned int* las_ptr;

__device__ __forceinline__ unsigned short f2bf(float f) {
  union { float f; unsigned u; } v; v.f = f;
  return (unsigned short)((v.u + 0x7fffu + ((v.u >> 16) & 1u)) >> 16);
}
__device__ __forceinline__ float bf2f(unsigned short s) {
  union { unsigned u; float f; } v; v.u = ((unsigned)s) << 16; return v.f;
}
__device__ __forceinline__ float sigmoidf_(float x) { return 1.f / (1.f + __expf(-x)); }
__device__ __forceinline__ float tanhf_(float x) { return 1.f - 2.f / (__expf(2.f * x) + 1.f); }

// coherent (LLC, sc0|sc1) accesses for h stores + flags; PROVEN protocol (v8-v10)
__device__ __forceinline__ void cohstore_u32(unsigned* p, unsigned v) {
  __hip_atomic_store(p, v, __ATOMIC_RELAXED, __HIP_MEMORY_SCOPE_AGENT);
}
__device__ __forceinline__ int cohload_i32(const int* p) {
  return __hip_atomic_load(p, __ATOMIC_RELAXED, __HIP_MEMORY_SCOPE_AGENT);
}
__device__ __forceinline__ void cohstore_i32(int* p, int v) {
  __hip_atomic_store(p, v, __ATOMIC_RELAXED, __HIP_MEMORY_SCOPE_AGENT);
}

__device__ __forceinline__ void gload_lds16(const void* g, void* l) {
  __builtin_amdgcn_global_load_lds((gas_ptr)g, (las_ptr)l, 16, 0, 0);
}

// stage a 16x512 bf16 tile into LDS via global_load_lds; swizzle lives in the
// per-lane global source (m173): elem(b,g) = g*128 + ((b^(g&15))*8).
__device__ __forceinline__ void stage_tile_gl(const unsigned short* __restrict__ src,
                                              unsigned short* __restrict__ dst, int tid) {
#pragma unroll
  for (int j = 0; j < 4; ++j) {
    int u = tid + j * 256;
    int g = u >> 4, b = (u & 15) ^ (g & 15);
    gload_lds16(src + (size_t)b * H_ + g * 8,
                dst + (size_t)((tid & ~63) + j * 256) * 8);
  }
}

// ---------------- convert: x [B,T,DIN] f32 -> xT [T,B,DIN] bf16 ----------------
__global__ void k_convert_x(const float* __restrict__ x, unsigned short* __restrict__ xT) {
  const int nq = T_ * B_ * DIN / 4;
  for (int q = blockIdx.x * blockDim.x + threadIdx.x; q < nq; q += gridDim.x * blockDim.x) {
    int e = q * 4;
    int d = e % DIN;
    int row = e / DIN;            // t*B + b
    int b = row & (B_ - 1), t = row / B_;
    float4 v = *(const float4*)(x + ((size_t)b * T_ + t) * DIN + d);
    unsigned short o[4] = { f2bf(v.x), f2bf(v.y), f2bf(v.z), f2bf(v.w) };
    *(uint2*)(xT + (size_t)row * DIN + d) = *(const uint2*)o;
  }
}

// ---------------- fused 2-layer persistent LSTM (v14 = v10 + dense flags + waved publish) ----------------
// Structure/protocol = v10. Changes:
// (1) DENSE flags: each group's 32 WG-flags are 32 consecutive dwords in ONE
//     cache line (write-through LLC => no false-sharing penalty); a poll
//     iteration is 1 transaction instead of 32. L0 groups also mirror their
//     flags to a second line so L1's combined poll stays 2 transactions.
// (2) Publish via per-wave LDS arrival counter: each wave drains its own
//     stores (vmcnt(0)) then atomicAdd; the 4th arriver fires the flag. No
//     full-WG publish barrier; cross-tick gbuf race closed by gbuf[2] parity.
__global__ __launch_bounds__(256, 1) void k_lstm14(
    const unsigned short* __restrict__ xT,   // [T,B,DIN] bf16
    const float* __restrict__ wih0, const float* __restrict__ whh0,
    const float* __restrict__ bih0, const float* __restrict__ bhh0,
    const float* __restrict__ wih1, const float* __restrict__ whh1,
    const float* __restrict__ bih1, const float* __restrict__ bhh1,
    unsigned short* __restrict__ h0, unsigned short* __restrict__ h1,  // [T,B,H]
    int* __restrict__ flg) {   // dense: line g = flg+g*64 (groups 0..7), mirrors 8..11
  __shared__ unsigned short hbufA[8192];   // 16KB h tile: elem g*128+((b^(g&15))*8)
  __shared__ unsigned short bufB[8192];    // 16KB: L0 = x dbuf [2][4096]; L1 = h1 tile
  __shared__ float gbuf[2][4 * 64 * 5];    // 10KB gate exchange, tick-parity dbuf
  __shared__ int wcnt;                     // monotone per-wave arrival counter
  const int bid = blockIdx.x;
  const int grp = bid & 7, cg = bid >> 3;
  const int layer = grp >> 2, bq = grp & 3;
  const int tid = threadIdx.x;
  const int lane = tid & 63, wv = tid >> 6;
  const int l15 = lane & 15, l4 = lane >> 4;
  const int colb = cg * 16, bb = bq * 16;
  const int ucol = tid & 15, ubat = tid >> 4;            // update cell (row=ubat,col=ucol)
  const int lp = (ubat >> 2) * 16 + ucol, ur = ubat & 3; // gbuf source for that cell
  int* f_my  = flg + grp * 64 + cg;            // my dword in the group's dense line
  int* f_myM = flg + (8 + bq) * 64 + cg;       // L0 mirror dword (L0 only)
  const int* f_own = flg + grp * 64;           // own group's dense line
  const int* f_l0  = flg + (8 + bq) * 64;      // L0 mirror line (L1 consumers)

  if (tid == 0) wcnt = 0;

  if (layer == 0) {
    // ================= LAYER 0 (x-fused; v10 body) =================
    short8 wih[8], whh[16];
    {
      const float* wr = wih0 + (size_t)(wv * H_ + colb + l15) * DIN + l4 * 8;
#pragma unroll
      for (int kk = 0; kk < 8; ++kk) {
        float4 v0 = *(const float4*)(wr + kk * 32);
        float4 v1 = *(const float4*)(wr + kk * 32 + 4);
        unsigned short o[8] = { f2bf(v0.x), f2bf(v0.y), f2bf(v0.z), f2bf(v0.w),
                                f2bf(v1.x), f2bf(v1.y), f2bf(v1.z), f2bf(v1.w) };
        wih[kk] = *(const short8*)o;
      }
      const float* wr2 = whh0 + (size_t)(wv * H_ + colb + l15) * H_ + l4 * 8;
#pragma unroll
      for (int kk = 0; kk < 16; ++kk) {
        float4 v0 = *(const float4*)(wr2 + kk * 32);
        float4 v1 = *(const float4*)(wr2 + kk * 32 + 4);
        unsigned short o[8] = { f2bf(v0.x), f2bf(v0.y), f2bf(v0.z), f2bf(v0.w),
                                f2bf(v1.x), f2bf(v1.y), f2bf(v1.z), f2bf(v1.w) };
        whh[kk] = *(const short8*)o;
      }
    }
    float b0s[4];
#pragma unroll
    for (int s = 0; s < 4; ++s)
      b0s[s] = bih0[s * H_ + colb + ucol] + bhh0[s * H_ + colb + ucol];
    float cst = 0.f;

    // prologue: stage x(0) into dbuf half 0
#pragma unroll
    for (int j = 0; j < 2; ++j) {
      int ch = tid + j * 256;
      int b = ch >> 5, g = ch & 31;
      uint4 v = *(const uint4*)(xT + (size_t)(bb + b) * DIN + g * 8);
      *(uint4*)&bufB[g * 128 + ((b ^ (g & 15)) * 8)] = v;
    }
    __syncthreads();

    for (int t = 0; t < T_; ++t) {
      // ---- 1. x-part MFMAs ----
      f32x4 aE = {}, aO = {};
      {
        const unsigned short* xb = bufB + (t & 1) * 4096;
#pragma unroll
        for (int kk = 0; kk < 8; kk += 2) {
          int g0 = kk * 4 + l4, g1 = (kk + 1) * 4 + l4;
          short8 a0 = *(const short8*)&xb[g0 * 128 + ((l15 ^ (g0 & 15)) * 8)];
          short8 a1 = *(const short8*)&xb[g1 * 128 + ((l15 ^ (g1 & 15)) * 8)];
          aE = __builtin_amdgcn_mfma_f32_16x16x32_bf16(a0, wih[kk], aE, 0, 0, 0);
          aO = __builtin_amdgcn_mfma_f32_16x16x32_bf16(a1, wih[kk + 1], aO, 0, 0, 0);
        }
      }
      // ---- 2. reg-prefetch x(t+1) ----
      uint4 xv[2];
      const bool hasx = (t + 1 < T_);
      if (hasx) {
        const unsigned short* xs = xT + (size_t)(t + 1) * (B_ * DIN);
#pragma unroll
        for (int j = 0; j < 2; ++j) {
          int ch = tid + j * 256;
          xv[j] = *(const uint4*)(xs + (size_t)(bb + (ch >> 5)) * DIN + (ch & 31) * 8);
        }
      }
      // ---- 3. wait h0(t-1): ONE dense line, then stage via global_load_lds ----
      if (t > 0) {
        for (;;) {
          int v = (lane < 32) ? cohload_i32(f_own + lane) : 0x7fffffff;
          if (__all(v >= t)) break;
        }
        __builtin_amdgcn_sched_barrier(0);
        asm volatile("" ::: "memory");
        stage_tile_gl(h0 + ((size_t)(t - 1) * B_ + bb) * H_, hbufA, tid);
      }
      // ---- 4. x(t+1) -> other dbuf half ----
      if (hasx) {
        unsigned short* xd = bufB + ((t + 1) & 1) * 4096;
#pragma unroll
        for (int j = 0; j < 2; ++j) {
          int ch = tid + j * 256;
          int b = ch >> 5, g = ch & 31;
          *(uint4*)&xd[g * 128 + ((b ^ (g & 15)) * 8)] = xv[j];
        }
      }
      __syncthreads();   // barrier 1: drains gload_lds (vmcnt) + x ds_writes
      // ---- 5. h-part MFMAs ----
      if (t > 0) {
#pragma unroll
        for (int kk = 0; kk < 16; kk += 2) {
          int g0 = kk * 4 + l4, g1 = (kk + 1) * 4 + l4;
          short8 a0 = *(const short8*)&hbufA[g0 * 128 + ((l15 ^ (g0 & 15)) * 8)];
          short8 a1 = *(const short8*)&hbufA[g1 * 128 + ((l15 ^ (g1 & 15)) * 8)];
          aE = __builtin_amdgcn_mfma_f32_16x16x32_bf16(a0, whh[kk], aE, 0, 0, 0);
          aO = __builtin_amdgcn_mfma_f32_16x16x32_bf16(a1, whh[kk + 1], aO, 0, 0, 0);
        }
      }
      f32x4 acc = aE + aO;
      // ---- 6. gate exchange (tick-parity buffer) ----
#pragma unroll
      for (int r = 0; r < 4; ++r) gbuf[t & 1][(wv * 64 + lane) * 5 + r] = acc[r];
      __syncthreads();   // barrier 2
      // ---- 7. update -> pack -> store; per-wave drain + LDS arrival publish ----
      {
        float g4[4];
#pragma unroll
        for (int s = 0; s < 4; ++s) g4[s] = gbuf[t & 1][(s * 64 + lp) * 5 + ur] + b0s[s];
        float iv = sigmoidf_(g4[0]), fv = sigmoidf_(g4[1]);
        float gv = tanhf_(g4[2]), ov = sigmoidf_(g4[3]);
        cst = fv * cst + iv * gv;
        unsigned short hv = f2bf(ov * tanhf_(cst));
        unsigned pv = (unsigned)hv | (((unsigned)__shfl_xor((int)hv, 1, 64)) << 16);
        if (!(lane & 1))
          cohstore_u32((unsigned*)(h0 + ((size_t)t * B_ + bb + ubat) * H_ + colb + ucol), pv);
      }
      asm volatile("s_waitcnt vmcnt(0)" ::: "memory");   // this wave's stores at LLC
      if (lane == 0) {
        int r = atomicAdd(&wcnt, 1);
        if (r == 4 * t + 3) {                            // all 4 waves drained
          cohstore_i32(f_my, t + 1);
          cohstore_i32(f_myM, t + 1);                    // mirror for L1 pollers
        }
      }
    }
  } else {
    // ================= LAYER 1 (v10 body: combined poll) =================
    short8 wA[16], wB[16];
    {
      const float* wrA = wih1 + (size_t)(wv * H_ + colb + l15) * H_ + l4 * 8;
      const float* wrB = whh1 + (size_t)(wv * H_ + colb + l15) * H_ + l4 * 8;
#pragma unroll
      for (int kk = 0; kk < 16; ++kk) {
        float4 a0 = *(const float4*)(wrA + kk * 32);
        float4 a1 = *(const float4*)(wrA + kk * 32 + 4);
        unsigned short oa[8] = { f2bf(a0.x), f2bf(a0.y), f2bf(a0.z), f2bf(a0.w),
                                 f2bf(a1.x), f2bf(a1.y), f2bf(a1.z), f2bf(a1.w) };
        wA[kk] = *(const short8*)oa;
        float4 b0 = *(const float4*)(wrB + kk * 32);
        float4 b1 = *(const float4*)(wrB + kk * 32 + 4);
        unsigned short ob[8] = { f2bf(b0.x), f2bf(b0.y), f2bf(b0.z), f2bf(b0.w),
                                 f2bf(b1.x), f2bf(b1.y), f2bf(b1.z), f2bf(b1.w) };
        wB[kk] = *(const short8*)ob;
      }
    }
    float b1s[4];
#pragma unroll
    for (int s = 0; s < 4; ++s)
      b1s[s] = bih1[s * H_ + colb + ucol] + bhh1[s * H_ + colb + ucol];
    float cst = 0.f;
    __syncthreads();   // wcnt init visible

    for (int t = 0; t < T_; ++t) {
      // ---- combined poll (2 dense lines): lanes 0..31 f_l0>=t+1, 32..63 f_own>=t ----
      {
        const int* fp = (lane < 32) ? (f_l0 + lane) : (f_own + (lane - 32));
        const int need = (lane < 32) ? (t + 1) : t;
        for (;;) {
          int v = cohload_i32(fp);
          if (__all(v >= need)) break;
        }
      }
      __builtin_amdgcn_sched_barrier(0);
      asm volatile("" ::: "memory");
      // ---- stage h0(t) and h1(t-1) concurrently via global_load_lds ----
      stage_tile_gl(h0 + ((size_t)t * B_ + bb) * H_, hbufA, tid);
      if (t > 0)
        stage_tile_gl(h1 + ((size_t)(t - 1) * B_ + bb) * H_, bufB, tid);
      __syncthreads();   // barrier 1: vmcnt drained
      // ---- all MFMAs (A: h0 @ Wih1, B: h1 @ Whh1) ----
      f32x4 aE = {}, aO = {}, bE = {}, bO = {};
      if (t > 0) {
#pragma unroll
        for (int kk = 0; kk < 16; kk += 2) {
          int g0 = kk * 4 + l4, g1 = (kk + 1) * 4 + l4;
          int e0 = g0 * 128 + ((l15 ^ (g0 & 15)) * 8);
          int e1 = g1 * 128 + ((l15 ^ (g1 & 15)) * 8);
          aE = __builtin_amdgcn_mfma_f32_16x16x32_bf16(*(const short8*)&hbufA[e0], wA[kk], aE, 0, 0, 0);
          aO = __builtin_amdgcn_mfma_f32_16x16x32_bf16(*(const short8*)&hbufA[e1], wA[kk + 1], aO, 0, 0, 0);
          bE = __builtin_amdgcn_mfma_f32_16x16x32_bf16(*(const short8*)&bufB[e0], wB[kk], bE, 0, 0, 0);
          bO = __builtin_amdgcn_mfma_f32_16x16x32_bf16(*(const short8*)&bufB[e1], wB[kk + 1], bO, 0, 0, 0);
        }
      } else {
#pragma unroll
        for (int kk = 0; kk < 16; kk += 2) {
          int g0 = kk * 4 + l4, g1 = (kk + 1) * 4 + l4;
          int e0 = g0 * 128 + ((l15 ^ (g0 & 15)) * 8);
          int e1 = g1 * 128 + ((l15 ^ (g1 & 15)) * 8);
          aE = __builtin_amdgcn_mfma_f32_16x16x32_bf16(*(const short8*)&hbufA[e0], wA[kk], aE, 0, 0, 0);
          aO = __builtin_amdgcn_mfma_f32_16x16x32_bf16(*(const short8*)&hbufA[e1], wA[kk + 1], aO, 0, 0, 0);
        }
      }
      f32x4 acc = (aE + aO) + (bE + bO);
      // ---- exchange (parity buffer) + update + publish ----
#pragma unroll
      for (int r = 0; r < 4; ++r) gbuf[t & 1][(wv * 64 + lane) * 5 + r] = acc[r];
      __syncthreads();   // barrier 2
      {
        float g4[4];
#pragma unroll
        for (int s = 0; s < 4; ++s) g4[s] = gbuf[t & 1][(s * 64 + lp) * 5 + ur] + b1s[s];
        float iv = sigmoidf_(g4[0]), fv = sigmoidf_(g4[1]);
        float gv = tanhf_(g4[2]), ov = sigmoidf_(g4[3]);
        cst = fv * cst + iv * gv;
        unsigned short hv = f2bf(ov * tanhf_(cst));
        unsigned pv = (unsigned)hv | (((unsigned)__shfl_xor((int)hv, 1, 64)) << 16);
        if (!(lane & 1))
          cohstore_u32((unsigned*)(h1 + ((size_t)t * B_ + bb + ubat) * H_ + colb + ucol), pv);
      }
      asm volatile("s_waitcnt vmcnt(0)" ::: "memory");
      if (lane == 0) {
        int r = atomicAdd(&wcnt, 1);
        if (r == 4 * t + 3) cohstore_i32(f_my, t + 1);
      }
    }
  }
}

// ---------------- final FC + sigmoid ----------------
__global__ void k_fc(const unsigned short* __restrict__ h1, const float* __restrict__ w,
                     const float* __restrict__ bfc, float* __restrict__ out) {
  int b = threadIdx.x;
  if (b < B_) {
    const unsigned short* hb = h1 + ((size_t)(T_ - 1) * B_ + b) * H_;
    float s = 0.f;
    for (int j = 0; j < H_; ++j) s += bf2f(hb[j]) * w[j];
    out[b] = sigmoidf_(s + bfc[0]);
  }
}

extern "C" void kernel_launch(void* const* d_in, const int* in_sizes, int n_in,
                              void* d_out, int out_size, void* d_ws, size_t ws_size,
                              hipStream_t stream) {
  (void)in_sizes; (void)n_in; (void)out_size; (void)ws_size;
  const float* x    = (const float*)d_in[0];
  const float* wih0 = (const float*)d_in[1];
  const float* whh0 = (const float*)d_in[2];
  const float* bih0 = (const float*)d_in[3];
  const float* bhh0 = (const float*)d_in[4];
  const float* wih1 = (const float*)d_in[5];
  const float* whh1 = (const float*)d_in[6];
  const float* bih1 = (const float*)d_in[7];
  const float* bhh1 = (const float*)d_in[8];
  const float* wfc  = (const float*)d_in[9];
  const float* bfc  = (const float*)d_in[10];
  float* out = (float*)d_out;

  const size_t HB = (size_t)T_ * B_ * H_ * 2;   // 33.55MB per layer
  char* ws = (char*)d_ws;
  int* flg = (int*)ws;                          // 12 dense lines x 64 ints = 3KB
  unsigned short* h0 = (unsigned short*)(ws + 4096);
  unsigned short* h1 = (unsigned short*)(ws + 4096 + HB);
  unsigned short* xT = (unsigned short*)(ws + 4096 + 2 * HB);

  hipMemsetAsync(flg, 0, 4096, stream);   // flags must start at 0 each replay
  k_convert_x<<<2048, 256, 0, stream>>>(x, xT);
  k_lstm14<<<NWGF, 256, 0, stream>>>(xT, wih0, whh0, bih0, bhh0,
                                     wih1, whh1, bih1, bhh1, h0, h1, flg);
  k_fc<<<1, 64, 0, stream>>>(h1, wfc, bfc, out);
}

// Round 15
// 1735.553 us; speedup vs baseline: 1.4003x; 1.4003x over previous
//
#include <hip/hip_runtime.h>
#include <stdint.h>
#include <stddef.h>

#define B_ 64
#define T_ 512
#define DIN 256
#define H_ 512
#define NWGF 256     // 8 groups (layer x batch-quarter) x 32 col-group WGs

typedef __attribute__((ext_vector_type(8))) short short8;
typedef __attribute__((ext_vector_type(4))) float f32x4;

typedef const __attribute__((address_space(1))) unsigned int* gas_ptr;
typedef __attribute__((address_space(3))) unsigned int* las_ptr;

__device__ __forceinline__ unsigned short f2bf(float f) {
  union { float f; unsigned u; } v; v.f = f;
  return (unsigned short)((v.u + 0x7fffu + ((v.u >> 16) & 1u)) >> 16);
}
__device__ __forceinline__ float bf2f(unsigned short s) {
  union { unsigned u; float f; } v; v.u = ((unsigned)s) << 16; return v.f;
}
__device__ __forceinline__ float sigmoidf_(float x) { return 1.f / (1.f + __expf(-x)); }
__device__ __forceinline__ float tanhf_(float x) { return 1.f - 2.f / (__expf(2.f * x) + 1.f); }

// coherent (LLC, sc0|sc1) accesses for h stores + flags; PROVEN protocol (v8-v10).
// Per-WG 128B flag lines are deliberate: centralized signals (shared counter r7,
// dense line r14) serialize at the LLC; distributed lines never contend.
__device__ __forceinline__ void cohstore_u32(unsigned* p, unsigned v) {
  __hip_atomic_store(p, v, __ATOMIC_RELAXED, __HIP_MEMORY_SCOPE_AGENT);
}
__device__ __forceinline__ int cohload_i32(const int* p) {
  return __hip_atomic_load(p, __ATOMIC_RELAXED, __HIP_MEMORY_SCOPE_AGENT);
}
__device__ __forceinline__ void cohstore_i32(int* p, int v) {
  __hip_atomic_store(p, v, __ATOMIC_RELAXED, __HIP_MEMORY_SCOPE_AGENT);
}

__device__ __forceinline__ void gload_lds16(const void* g, void* l) {
  __builtin_amdgcn_global_load_lds((gas_ptr)g, (las_ptr)l, 16, 0, 0);
}

// stage a 16x512 bf16 tile into LDS via global_load_lds: LDS dest is linear
// (wave-uniform base + lane*16 by HW); the SWIZZLE lives in the per-lane global
// source index (m173 pattern). Forward map: elem(b,g) = g*128 + ((b^(g&15))*8).
// Inverse for linear chunk u: g = u>>4, b = (u&15)^(g&15).
__device__ __forceinline__ void stage_tile_gl(const unsigned short* __restrict__ src,
                                              unsigned short* __restrict__ dst, int tid) {
#pragma unroll
  for (int j = 0; j < 4; ++j) {
    int u = tid + j * 256;
    int g = u >> 4, b = (u & 15) ^ (g & 15);
    gload_lds16(src + (size_t)b * H_ + g * 8,
                dst + (size_t)((tid & ~63) + j * 256) * 8);
  }
}

// ---------------- convert: x [B,T,DIN] f32 -> xT [T,B,DIN] bf16 ----------------
__global__ void k_convert_x(const float* __restrict__ x, unsigned short* __restrict__ xT) {
  const int nq = T_ * B_ * DIN / 4;
  for (int q = blockIdx.x * blockDim.x + threadIdx.x; q < nq; q += gridDim.x * blockDim.x) {
    int e = q * 4;
    int d = e % DIN;
    int row = e / DIN;            // t*B + b
    int b = row & (B_ - 1), t = row / B_;
    float4 v = *(const float4*)(x + ((size_t)b * T_ + t) * DIN + d);
    unsigned short o[4] = { f2bf(v.x), f2bf(v.y), f2bf(v.z), f2bf(v.w) };
    *(uint2*)(xT + (size_t)row * DIN + d) = *(const uint2*)o;
  }
}

// ---------------- fused 2-layer persistent LSTM (v15 = v10, the measured floor) ----------------
// 8 groups (layer x batch-quarter) x 32 col-WGs, 1 WG/CU. Per-tick protocol:
// coherent h stores -> vmcnt(0) -> barrier -> per-WG flag line; consumers poll
// the 32 flag lines, stage via global_load_lds (cached path, first touch
// post-flag), MFMA from swizzled LDS. Latency-bound at ~3.4us/tick (~3 MALL RTs
// + stage + compute); alternatives measured worse in r9/r11-r14.
__global__ __launch_bounds__(256, 1) void k_lstm10(
    const unsigned short* __restrict__ xT,   // [T,B,DIN] bf16
    const float* __restrict__ wih0, const float* __restrict__ whh0,
    const float* __restrict__ bih0, const float* __restrict__ bhh0,
    const float* __restrict__ wih1, const float* __restrict__ whh1,
    const float* __restrict__ bih1, const float* __restrict__ bhh1,
    unsigned short* __restrict__ h0, unsigned short* __restrict__ h1,  // [T,B,H]
    int* __restrict__ flg) {                 // 256 WGs x 128B flag lines
  __shared__ unsigned short hbufA[8192];   // 16KB h tile: elem g*128+((b^(g&15))*8)
  __shared__ unsigned short bufB[8192];    // 16KB: L0 = x dbuf [2][4096]; L1 = h1 tile
  __shared__ float gbuf[4 * 64 * 5];       // 5KB gate exchange (stride-5)
  const int bid = blockIdx.x;
  const int grp = bid & 7, cg = bid >> 3;
  const int layer = grp >> 2, bq = grp & 3;
  const int tid = threadIdx.x;
  const int lane = tid & 63, wv = tid >> 6;
  const int l15 = lane & 15, l4 = lane >> 4;
  const int colb = cg * 16, bb = bq * 16;
  const int ucol = tid & 15, ubat = tid >> 4;            // update cell (row=ubat,col=ucol)
  const int lp = (ubat >> 2) * 16 + ucol, ur = ubat & 3; // gbuf source for that cell
  int* myflag = flg + (grp * 32 + cg) * 32;
  const int* f_own = flg + (grp * 32) * 32;              // own group's flag block
  const int* f_l0  = flg + (bq * 32) * 32;               // layer-0 group (for L1)

  if (layer == 0) {
    // ================= LAYER 0 (x-fused) =================
    short8 wih[8], whh[16];
    {
      const float* wr = wih0 + (size_t)(wv * H_ + colb + l15) * DIN + l4 * 8;
#pragma unroll
      for (int kk = 0; kk < 8; ++kk) {
        float4 v0 = *(const float4*)(wr + kk * 32);
        float4 v1 = *(const float4*)(wr + kk * 32 + 4);
        unsigned short o[8] = { f2bf(v0.x), f2bf(v0.y), f2bf(v0.z), f2bf(v0.w),
                                f2bf(v1.x), f2bf(v1.y), f2bf(v1.z), f2bf(v1.w) };
        wih[kk] = *(const short8*)o;
      }
      const float* wr2 = whh0 + (size_t)(wv * H_ + colb + l15) * H_ + l4 * 8;
#pragma unroll
      for (int kk = 0; kk < 16; ++kk) {
        float4 v0 = *(const float4*)(wr2 + kk * 32);
        float4 v1 = *(const float4*)(wr2 + kk * 32 + 4);
        unsigned short o[8] = { f2bf(v0.x), f2bf(v0.y), f2bf(v0.z), f2bf(v0.w),
                                f2bf(v1.x), f2bf(v1.y), f2bf(v1.z), f2bf(v1.w) };
        whh[kk] = *(const short8*)o;
      }
    }
    float b0s[4];
#pragma unroll
    for (int s = 0; s < 4; ++s)
      b0s[s] = bih0[s * H_ + colb + ucol] + bhh0[s * H_ + colb + ucol];
    float cst = 0.f;

    // prologue: stage x(0) into dbuf half 0 (16 rows x 32 granules)
#pragma unroll
    for (int j = 0; j < 2; ++j) {
      int ch = tid + j * 256;
      int b = ch >> 5, g = ch & 31;
      uint4 v = *(const uint4*)(xT + (size_t)(bb + b) * DIN + g * 8);
      *(uint4*)&bufB[g * 128 + ((b ^ (g & 15)) * 8)] = v;
    }
    __syncthreads();

    for (int t = 0; t < T_; ++t) {
      // ---- 1. x-part MFMAs (hides detect of step 3) ----
      f32x4 aE = {}, aO = {};
      {
        const unsigned short* xb = bufB + (t & 1) * 4096;
#pragma unroll
        for (int kk = 0; kk < 8; kk += 2) {
          int g0 = kk * 4 + l4, g1 = (kk + 1) * 4 + l4;
          short8 a0 = *(const short8*)&xb[g0 * 128 + ((l15 ^ (g0 & 15)) * 8)];
          short8 a1 = *(const short8*)&xb[g1 * 128 + ((l15 ^ (g1 & 15)) * 8)];
          aE = __builtin_amdgcn_mfma_f32_16x16x32_bf16(a0, wih[kk], aE, 0, 0, 0);
          aO = __builtin_amdgcn_mfma_f32_16x16x32_bf16(a1, wih[kk + 1], aO, 0, 0, 0);
        }
      }
      // ---- 2. reg-prefetch x(t+1) (in flight during the wait) ----
      uint4 xv[2];
      const bool hasx = (t + 1 < T_);
      if (hasx) {
        const unsigned short* xs = xT + (size_t)(t + 1) * (B_ * DIN);
#pragma unroll
        for (int j = 0; j < 2; ++j) {
          int ch = tid + j * 256;
          xv[j] = *(const uint4*)(xs + (size_t)(bb + (ch >> 5)) * DIN + (ch & 31) * 8);
        }
      }
      // ---- 3. wait h0(t-1) flags, stage via global_load_lds ----
      if (t > 0) {
        for (;;) {
          int v = (lane < 32) ? cohload_i32(f_own + lane * 32) : 0x7fffffff;
          if (__all(v >= t)) break;
        }
        __builtin_amdgcn_sched_barrier(0);
        asm volatile("" ::: "memory");
        stage_tile_gl(h0 + ((size_t)(t - 1) * B_ + bb) * H_, hbufA, tid);
      }
      // ---- 4. x(t+1) -> other dbuf half ----
      if (hasx) {
        unsigned short* xd = bufB + ((t + 1) & 1) * 4096;
#pragma unroll
        for (int j = 0; j < 2; ++j) {
          int ch = tid + j * 256;
          int b = ch >> 5, g = ch & 31;
          *(uint4*)&xd[g * 128 + ((b ^ (g & 15)) * 8)] = xv[j];
        }
      }
      __syncthreads();   // barrier 1: drains gload_lds (vmcnt) + x ds_writes
      // ---- 5. h-part MFMAs ----
      if (t > 0) {
#pragma unroll
        for (int kk = 0; kk < 16; kk += 2) {
          int g0 = kk * 4 + l4, g1 = (kk + 1) * 4 + l4;
          short8 a0 = *(const short8*)&hbufA[g0 * 128 + ((l15 ^ (g0 & 15)) * 8)];
          short8 a1 = *(const short8*)&hbufA[g1 * 128 + ((l15 ^ (g1 & 15)) * 8)];
          aE = __builtin_amdgcn_mfma_f32_16x16x32_bf16(a0, whh[kk], aE, 0, 0, 0);
          aO = __builtin_amdgcn_mfma_f32_16x16x32_bf16(a1, whh[kk + 1], aO, 0, 0, 0);
        }
      }
      f32x4 acc = aE + aO;
      // ---- 6. gate exchange ----
#pragma unroll
      for (int r = 0; r < 4; ++r) gbuf[(wv * 64 + lane) * 5 + r] = acc[r];
      __syncthreads();   // barrier 2
      // ---- 7. cell update -> shfl-pack -> direct u32 coherent store ----
      {
        float g4[4];
#pragma unroll
        for (int s = 0; s < 4; ++s) g4[s] = gbuf[(s * 64 + lp) * 5 + ur] + b0s[s];
        float iv = sigmoidf_(g4[0]), fv = sigmoidf_(g4[1]);
        float gv = tanhf_(g4[2]), ov = sigmoidf_(g4[3]);
        cst = fv * cst + iv * gv;
        unsigned short hv = f2bf(ov * tanhf_(cst));
        unsigned pv = (unsigned)hv | (((unsigned)__shfl_xor((int)hv, 1, 64)) << 16);
        if (!(lane & 1))
          cohstore_u32((unsigned*)(h0 + ((size_t)t * B_ + bb + ubat) * H_ + colb + ucol), pv);
      }
      asm volatile("s_waitcnt vmcnt(0)" ::: "memory");
      __syncthreads();   // barrier 3: all threads' stores drained
      if (tid == 0) cohstore_i32(myflag, t + 1);
    }
  } else {
    // ================= LAYER 1 =================
    short8 wA[16], wB[16];
    {
      const float* wrA = wih1 + (size_t)(wv * H_ + colb + l15) * H_ + l4 * 8;
      const float* wrB = whh1 + (size_t)(wv * H_ + colb + l15) * H_ + l4 * 8;
#pragma unroll
      for (int kk = 0; kk < 16; ++kk) {
        float4 a0 = *(const float4*)(wrA + kk * 32);
        float4 a1 = *(const float4*)(wrA + kk * 32 + 4);
        unsigned short oa[8] = { f2bf(a0.x), f2bf(a0.y), f2bf(a0.z), f2bf(a0.w),
                                 f2bf(a1.x), f2bf(a1.y), f2bf(a1.z), f2bf(a1.w) };
        wA[kk] = *(const short8*)oa;
        float4 b0 = *(const float4*)(wrB + kk * 32);
        float4 b1 = *(const float4*)(wrB + kk * 32 + 4);
        unsigned short ob[8] = { f2bf(b0.x), f2bf(b0.y), f2bf(b0.z), f2bf(b0.w),
                                 f2bf(b1.x), f2bf(b1.y), f2bf(b1.z), f2bf(b1.w) };
        wB[kk] = *(const short8*)ob;
      }
    }
    float b1s[4];
#pragma unroll
    for (int s = 0; s < 4; ++s)
      b1s[s] = bih1[s * H_ + colb + ucol] + bhh1[s * H_ + colb + ucol];
    float cst = 0.f;

    for (int t = 0; t < T_; ++t) {
      // ---- combined poll: lanes 0..31 watch f_l0 >= t+1, lanes 32..63 watch f_own >= t ----
      {
        const int* fp = (lane < 32) ? (f_l0 + lane * 32) : (f_own + (lane - 32) * 32);
        const int need = (lane < 32) ? (t + 1) : t;
        for (;;) {
          int v = cohload_i32(fp);
          if (__all(v >= need)) break;
        }
      }
      __builtin_amdgcn_sched_barrier(0);
      asm volatile("" ::: "memory");
      // ---- stage h0(t) and h1(t-1) concurrently via global_load_lds ----
      stage_tile_gl(h0 + ((size_t)t * B_ + bb) * H_, hbufA, tid);
      if (t > 0)
        stage_tile_gl(h1 + ((size_t)(t - 1) * B_ + bb) * H_, bufB, tid);
      __syncthreads();   // barrier 1: vmcnt drained
      // ---- all MFMAs (A: h0 @ Wih1, B: h1 @ Whh1), 4 independent chains ----
      f32x4 aE = {}, aO = {}, bE = {}, bO = {};
      if (t > 0) {
#pragma unroll
        for (int kk = 0; kk < 16; kk += 2) {
          int g0 = kk * 4 + l4, g1 = (kk + 1) * 4 + l4;
          int e0 = g0 * 128 + ((l15 ^ (g0 & 15)) * 8);
          int e1 = g1 * 128 + ((l15 ^ (g1 & 15)) * 8);
          aE = __builtin_amdgcn_mfma_f32_16x16x32_bf16(*(const short8*)&hbufA[e0], wA[kk], aE, 0, 0, 0);
          aO = __builtin_amdgcn_mfma_f32_16x16x32_bf16(*(const short8*)&hbufA[e1], wA[kk + 1], aO, 0, 0, 0);
          bE = __builtin_amdgcn_mfma_f32_16x16x32_bf16(*(const short8*)&bufB[e0], wB[kk], bE, 0, 0, 0);
          bO = __builtin_amdgcn_mfma_f32_16x16x32_bf16(*(const short8*)&bufB[e1], wB[kk + 1], bO, 0, 0, 0);
        }
      } else {
#pragma unroll
        for (int kk = 0; kk < 16; kk += 2) {
          int g0 = kk * 4 + l4, g1 = (kk + 1) * 4 + l4;
          int e0 = g0 * 128 + ((l15 ^ (g0 & 15)) * 8);
          int e1 = g1 * 128 + ((l15 ^ (g1 & 15)) * 8);
          aE = __builtin_amdgcn_mfma_f32_16x16x32_bf16(*(const short8*)&hbufA[e0], wA[kk], aE, 0, 0, 0);
          aO = __builtin_amdgcn_mfma_f32_16x16x32_bf16(*(const short8*)&hbufA[e1], wA[kk + 1], aO, 0, 0, 0);
        }
      }
      f32x4 acc = (aE + aO) + (bE + bO);
      // ---- exchange + update + pack-store + publish ----
#pragma unroll
      for (int r = 0; r < 4; ++r) gbuf[(wv * 64 + lane) * 5 + r] = acc[r];
      __syncthreads();   // barrier 2
      {
        float g4[4];
#pragma unroll
        for (int s = 0; s < 4; ++s) g4[s] = gbuf[(s * 64 + lp) * 5 + ur] + b1s[s];
        float iv = sigmoidf_(g4[0]), fv = sigmoidf_(g4[1]);
        float gv = tanhf_(g4[2]), ov = sigmoidf_(g4[3]);
        cst = fv * cst + iv * gv;
        unsigned short hv = f2bf(ov * tanhf_(cst));
        unsigned pv = (unsigned)hv | (((unsigned)__shfl_xor((int)hv, 1, 64)) << 16);
        if (!(lane & 1))
          cohstore_u32((unsigned*)(h1 + ((size_t)t * B_ + bb + ubat) * H_ + colb + ucol), pv);
      }
      asm volatile("s_waitcnt vmcnt(0)" ::: "memory");
      __syncthreads();   // barrier 3
      if (tid == 0) cohstore_i32(myflag, t + 1);
    }
  }
}

// ---------------- final FC + sigmoid ----------------
__global__ void k_fc(const unsigned short* __restrict__ h1, const float* __restrict__ w,
                     const float* __restrict__ bfc, float* __restrict__ out) {
  int b = threadIdx.x;
  if (b < B_) {
    const unsigned short* hb = h1 + ((size_t)(T_ - 1) * B_ + b) * H_;
    float s = 0.f;
    for (int j = 0; j < H_; ++j) s += bf2f(hb[j]) * w[j];
    out[b] = sigmoidf_(s + bfc[0]);
  }
}

extern "C" void kernel_launch(void* const* d_in, const int* in_sizes, int n_in,
                              void* d_out, int out_size, void* d_ws, size_t ws_size,
                              hipStream_t stream) {
  (void)in_sizes; (void)n_in; (void)out_size; (void)ws_size;
  const float* x    = (const float*)d_in[0];
  const float* wih0 = (const float*)d_in[1];
  const float* whh0 = (const float*)d_in[2];
  const float* bih0 = (const float*)d_in[3];
  const float* bhh0 = (const float*)d_in[4];
  const float* wih1 = (const float*)d_in[5];
  const float* whh1 = (const float*)d_in[6];
  const float* bih1 = (const float*)d_in[7];
  const float* bhh1 = (const float*)d_in[8];
  const float* wfc  = (const float*)d_in[9];
  const float* bfc  = (const float*)d_in[10];
  float* out = (float*)d_out;

  const size_t HB = (size_t)T_ * B_ * H_ * 2;   // 33.55MB per layer
  char* ws = (char*)d_ws;
  int* flg = (int*)ws;                          // 256 x 128B flag lines = 32KB
  unsigned short* h0 = (unsigned short*)(ws + 32768);
  unsigned short* h1 = (unsigned short*)(ws + 32768 + HB);
  unsigned short* xT = (unsigned short*)(ws + 32768 + 2 * HB);

  hipMemsetAsync(ws, 0, 32768, stream);   // flags must start at 0 each replay
  k_convert_x<<<2048, 256, 0, stream>>>(x, xT);
  k_lstm10<<<NWGF, 256, 0, stream>>>(xT, wih0, whh0, bih0, bhh0,
                                     wih1, whh1, bih1, bhh1, h0, h1, flg);
  k_fc<<<1, 64, 0, stream>>>(h1, wfc, bfc, out);
}